// Round 4
// baseline (311.057 us; speedup 1.0000x reference)
//
#include <hip/hip_runtime.h>
#include <math.h>

#define NTOK 4096

typedef __attribute__((ext_vector_type(8))) short short8;
typedef __attribute__((ext_vector_type(4))) float floatx4;

static __device__ __forceinline__ unsigned short f2bf(float f) {
    unsigned int u = __float_as_uint(f);
    unsigned int r = (u + 0x7fffu + ((u >> 16) & 1u)) >> 16;
    return (unsigned short)r;
}

static __device__ __forceinline__ float bf2f(unsigned short s) {
    return __uint_as_float((unsigned)s << 16);
}

// async global->LDS, 16B per lane. LDS dest = wave-uniform base + lane*16.
static __device__ __forceinline__ void gload16(const void* g, void* l) {
    __builtin_amdgcn_global_load_lds(
        (const __attribute__((address_space(1))) void*)g,
        (__attribute__((address_space(3))) void*)(unsigned int)(unsigned long long)l,
        16, 0, 0);
}

// 16-lane (DPP row) sum butterfly: all lanes of each 16-lane group end with the
// group sum. VALU-only -- no LDS-pipe contention with main-loop ds_read_b128.
static __device__ __forceinline__ float row16_sum(float x) {
    x += __int_as_float(__builtin_amdgcn_update_dpp(0, __float_as_int(x), 0xB1, 0xF, 0xF, true));  // quad_perm xor1
    x += __int_as_float(__builtin_amdgcn_update_dpp(0, __float_as_int(x), 0x4E, 0xF, 0xF, true));  // quad_perm xor2
    x += __int_as_float(__builtin_amdgcn_update_dpp(0, __float_as_int(x), 0x141, 0xF, 0xF, true)); // row_half_mirror
    x += __int_as_float(__builtin_amdgcn_update_dpp(0, __float_as_int(x), 0x140, 0xF, 0xF, true)); // row_mirror
    return x;
}

#define WAIT_VM12() asm volatile("s_waitcnt vmcnt(12)" ::: "memory")
#define WAIT_VM8()  asm volatile("s_waitcnt vmcnt(8)" ::: "memory")
#define WAIT_VM6()  asm volatile("s_waitcnt vmcnt(6)" ::: "memory")
#define WAIT_VM4()  asm volatile("s_waitcnt vmcnt(4)" ::: "memory")
#define WAIT_VM0()  asm volatile("s_waitcnt vmcnt(0)" ::: "memory")
#define WAIT_LGKM() asm volatile("s_waitcnt lgkmcnt(0)" ::: "memory")

// ce stage: A 256x32 (16KB) + B 128x32 (8KB); 3 stages
#define ASTG 8192   // shorts per A stage
#define BSTG 4096   // shorts per B stage
// hgemm stage: 128x32 A and B (8KB each)
#define STG 4096

// ---------------- prep: compact (blocks 0..15) + cvt of win/t0w1/t1w1 ----------------
// flat-indexed cvt: block allocation proportional to array size (no per-array tail).
__global__ __launch_bounds__(256)
void prep_k(const float* __restrict__ w_in, unsigned short* __restrict__ win_bf,
            const float* __restrict__ t0w1, unsigned short* __restrict__ t0w1_bf,
            const float* __restrict__ t1w1, unsigned short* __restrict__ t1w1_bf,
            const int* __restrict__ target,
            int* __restrict__ idx0, int* __restrict__ lab0, int* __restrict__ n0,
            int* __restrict__ idx1, int* __restrict__ lab1, int* __restrict__ n1,
            int* __restrict__ labh) {
    int bid = blockIdx.x;
    if (bid < 16) {
        int i = bid * 256 + threadIdx.x;   // 4096 threads exactly, wave-uniform
        int t = target[i];
        int lane = threadIdx.x & 63;
        unsigned long long below = (1ull << lane) - 1ull;
        bool m0 = (t >= 2000) && (t < 10000);
        bool m1 = (t >= 10000);
        unsigned long long b0 = __ballot(m0);
        unsigned long long b1 = __ballot(m1);
        int ft = t;
        // wave-aggregated compaction: 1 atomic per wave per counter.
        if (m0) {
            int ldr = __ffsll((long long)b0) - 1;
            int base = 0;
            if (lane == ldr) base = atomicAdd(n0, __popcll(b0));
            base = __shfl(base, ldr, 64);
            int p = base + __popcll(b0 & below);
            idx0[p] = i; lab0[p] = t - 2000; ft = 2000;
        } else if (m1) {
            int ldr = __ffsll((long long)b1) - 1;
            int base = 0;
            if (lane == ldr) base = atomicAdd(n1, __popcll(b1));
            base = __shfl(base, ldr, 64);
            int p = base + __popcll(b1 & below);
            idx1[p] = i; lab1[p] = t - 10000; ft = 2001;
        }
        labh[i] = ft;
        return;
    }
    // cvt: flat float4 index over [w_in | t0w1 | t1w1]
    const int E0 = 4194304, E1 = E0 + 1048576, TOT = E1 + 262144;   // floats
    int gi = (bid - 16) * 256 + threadIdx.x;
    int stride = (gridDim.x - 16) * 256;
    for (int i4 = gi; i4 * 4 < TOT; i4 += stride) {
        int i = i4 * 4;
        const float* s; unsigned short* d; int off;
        if (i < E0)      { s = w_in;  d = win_bf;  off = i; }
        else if (i < E1) { s = t0w1; d = t0w1_bf; off = i - E0; }
        else             { s = t1w1; d = t1w1_bf; off = i - E1; }
        float4 v = *(const float4*)(s + off);
        ushort4 o;
        o.x = f2bf(v.x); o.y = f2bf(v.y); o.z = f2bf(v.z); o.w = f2bf(v.w);
        *(ushort4*)(d + off) = o;
    }
}

// ---------------- merged gathered h-GEMM (blocks 0..319) + cvt of hw/t0w2/t1w2 ----------------
// hgemm only has ~100 active blocks (>60% of CUs idle) -- the cvt blocks fill
// the rest of the machine, overlapping 102MB of pure-BW work with the GEMM.
__global__ __launch_bounds__(256)
void hgemm_cvt_k(const unsigned short* __restrict__ win,
                 const unsigned short* __restrict__ t0w1, unsigned short* __restrict__ h0o,
                 const int* __restrict__ idx0, const int* __restrict__ n0p,
                 const unsigned short* __restrict__ t1w1, unsigned short* __restrict__ h1o,
                 const int* __restrict__ idx1, const int* __restrict__ n1p,
                 const float* __restrict__ head_w, unsigned short* __restrict__ hw_bf,
                 const float* __restrict__ t0w2, unsigned short* __restrict__ t0w2_bf,
                 const float* __restrict__ t1w2, unsigned short* __restrict__ t1w2_bf) {
    __shared__ unsigned short Asm[3 * STG];
    __shared__ unsigned short Bsm[3 * STG];
    __shared__ int sidx[128];
    int bid = blockIdx.x;
    if (bid >= 320) {
        const int E0 = 2050048, E1 = E0 + 8192000, TOT = E1 + 10240000;   // floats
        int gi = (bid - 320) * 256 + threadIdx.x;
        int stride = (gridDim.x - 320) * 256;
        for (int i4 = gi; i4 * 4 < TOT; i4 += stride) {
            int i = i4 * 4;
            const float* s; unsigned short* d; int off;
            if (i < E0)      { s = head_w; d = hw_bf;   off = i; }
            else if (i < E1) { s = t0w2;  d = t0w2_bf; off = i - E0; }
            else             { s = t1w2;  d = t1w2_bf; off = i - E1; }
            float4 v = *(const float4*)(s + off);
            ushort4 o;
            o.x = f2bf(v.x); o.y = f2bf(v.y); o.z = f2bf(v.z); o.w = f2bf(v.w);
            *(ushort4*)(d + off) = o;
        }
        return;
    }
    const unsigned short* B; unsigned short* H; const int* idx; int n, P, rb, cb;
    if (bid < 256) { rb = bid >> 3; cb = bid & 7; B = t0w1; H = h0o; idx = idx0; n = *n0p; P = 1024; }
    else { int b = bid - 256; rb = b >> 1; cb = b & 1; B = t1w1; H = h1o; idx = idx1; n = *n1p; P = 256; }
    const int K = 1024, T = 32;
    int row_base = rb * 128;
    if (row_base >= n) return;
    int col_base = cb * 128;
    int t = threadIdx.x;
    int wave = t >> 6, lane = t & 63;
    int wrow = (wave >> 1) * 64, wcol = (wave & 1) * 64;
    int fr = lane & 15, fk = lane >> 4;

    if (t < 128) { int r = row_base + t; sidx[t] = idx[r < n ? r : n - 1]; }
    __syncthreads();   // drains vmcnt: clean slate before manual pipeline (gather needs sidx)

    int sr0 = wave * 32 + (lane >> 2);
    int sr1 = sr0 + 16;
    int c0l = lane & 3;
    int gc0 = c0l ^ ((sr0 >> 1) & 3);
    int gc1 = c0l ^ ((sr1 >> 1) & 3);
    const unsigned short* Ab0 = win + (size_t)sidx[sr0] * K + gc0 * 8;
    const unsigned short* Ab1 = win + (size_t)sidx[sr1] * K + gc1 * 8;
    const unsigned short* Bb0 = B + (size_t)(col_base + sr0) * K + gc0 * 8;
    const unsigned short* Bb1 = B + (size_t)(col_base + sr1) * K + gc1 * 8;

    auto issue = [&](int s, int slot) {
        int koff = s << 5;
        unsigned short* as = Asm + slot * STG + wave * 1024;
        unsigned short* bs = Bsm + slot * STG + wave * 1024;
        gload16(Ab0 + koff, as); gload16(Ab1 + koff, as + 512);
        gload16(Bb0 + koff, bs); gload16(Bb1 + koff, bs + 512);
    };

    int sw = (fk ^ ((fr >> 1) & 3)) * 8;
    int ra[4], rc[4];
#pragma unroll
    for (int i = 0; i < 4; ++i) {
        ra[i] = (wrow + i * 16 + fr) * 32 + sw;
        rc[i] = (wcol + i * 16 + fr) * 32 + sw;
    }

    issue(0, 0); issue(1, 1);
    floatx4 acc[4][4] = {};
    int sc = 0, si = 2;
    for (int j = 0; j < T; ++j) {
        if (j + 2 < T) { issue(j + 2, si); si = (si == 2) ? 0 : si + 1; }
        int rem = T - 1 - j;
        if (rem >= 2) { WAIT_VM8(); }
        else if (rem == 1) { WAIT_VM4(); }
        else { WAIT_VM0(); }
        WAIT_LGKM();
        __builtin_amdgcn_s_barrier();
        const unsigned short* As = Asm + sc * STG;
        const unsigned short* Bs = Bsm + sc * STG;
        sc = (sc == 2) ? 0 : sc + 1;
        short8 af[4], bf[4];
#pragma unroll
        for (int i = 0; i < 4; ++i) af[i] = *(const short8*)&As[ra[i]];
#pragma unroll
        for (int i = 0; i < 4; ++i) bf[i] = *(const short8*)&Bs[rc[i]];
#pragma unroll
        for (int rt = 0; rt < 4; ++rt)
#pragma unroll
            for (int ct = 0; ct < 4; ++ct)
                acc[rt][ct] = __builtin_amdgcn_mfma_f32_16x16x32_bf16(af[rt], bf[ct], acc[rt][ct], 0, 0, 0);
    }
#pragma unroll
    for (int rt = 0; rt < 4; ++rt)
#pragma unroll
        for (int r = 0; r < 4; ++r) {
            int row = row_base + wrow + rt * 16 + fk * 4 + r;
#pragma unroll
            for (int ct = 0; ct < 4; ++ct) {
                int col = col_base + wcol + ct * 16 + fr;
                H[(size_t)row * P + col] = f2bf(acc[rt][ct][r]);
            }
        }
}

// ---------------- CE: panel-persistent 256x128 tiles ----------------
// Round-4 restructure: each block owns ONE column-chunk (B panel) and loops
// over up to 4 row-blocks (rb = g, g+4, g+8, g+12). The panel is re-read
// sequentially -> L2-hot after run 0. The 4 blocks sharing a panel are placed
// at bids congruent mod 8, so under round-robin block->XCD dispatch they share
// one XCD L2 (heuristic only -- correctness never depends on it).
// Panel decode: x=bid&7, sl=bid>>3, g=sl&3, pan=(sl>>2)*8+x (0..391):
//   pan <16  : head  V=2002  K=1024 T=32 (longest blocks -> lowest bids, dispatched first)
//   pan <79  : tail0 V=8000  K=1024 T=32
//   else     : tail1 V=40000 K=256  T=8
// Cross-run pipeline: next run's stage0/1 prefetch issues BEFORE the epilogue
// (after a raw-barrier fence; no vmcnt drain anywhere between runs except the
// T-loop's own counted waits). The epilogue ps-store adds one vm op to the
// queue; the 12/6/0 wait constants still cover the needed stage (re-derived:
// at j=0 wait vm12 completes st0(6)+1 extra; at j=1 completes st1 rest+store).
__global__ __launch_bounds__(256, 2)
void ce_all_k(const unsigned short* __restrict__ h1, const unsigned short* __restrict__ t1w2,
              const int* __restrict__ n1p, float* __restrict__ ps1,
              const unsigned short* __restrict__ h0, const unsigned short* __restrict__ t0w2,
              const int* __restrict__ n0p, float* __restrict__ ps0,
              const unsigned short* __restrict__ win, const unsigned short* __restrict__ hw,
              const float* __restrict__ head_b, float* __restrict__ psh) {
    __shared__ unsigned short Asm[3 * ASTG];
    __shared__ unsigned short Bsm[3 * BSTG];
    __shared__ float cs[256][2];
    int bid = blockIdx.x;
    int x = bid & 7, sl = bid >> 3;
    int g = sl & 3;
    int pan = (sl >> 2) * 8 + x;   // 0..391
    const unsigned short* A; const unsigned short* B; const float* bias = nullptr;
    int n, V, kbits, T, ch;
    float* ps;
    if (pan < 16) {
        ch = pan;      A = win; B = hw;   n = NTOK; V = 2002;  kbits = 10; T = 32; ps = psh; bias = head_b;
    } else if (pan < 79) {
        ch = pan - 16; A = h0;  B = t0w2; n = *n0p; V = 8000;  kbits = 10; T = 32; ps = ps0;
    } else {
        ch = pan - 79; A = h1;  B = t1w2; n = *n1p; V = 40000; kbits = 8;  T = 8;  ps = ps1;
    }
    if (g * 256 >= n) return;   // rb indices only grow -> whole block idle
    int colb = ch << 7;
    int Vm1 = V - 1;
    int t = threadIdx.x;
    int wave = t >> 6, lane = t & 63;
    int wrow = (wave >> 1) * 128, wcol = (wave & 1) * 64;
    int fr = lane & 15, fk = lane >> 4;

    // staging: A 256x32 (4 instr/wave, 16-row steps), B 128x32 (2 instr/wave)
    int sra = wave * 64 + (lane >> 2);
    int srb = wave * 32 + (lane >> 2);
    int c0l = lane & 3;
    int gca = c0l ^ ((sra >> 1) & 3);   // +16 row steps preserve (r>>1)&3
    int gcb = c0l ^ ((srb >> 1) & 3);
    const unsigned short* Ab0 = A + (((size_t)sra) << kbits) + gca * 8;         // + row offset at issue
    const unsigned short* Ab1 = A + (((size_t)(sra + 16)) << kbits) + gca * 8;
    const unsigned short* Ab2 = A + (((size_t)(sra + 32)) << kbits) + gca * 8;
    const unsigned short* Ab3 = A + (((size_t)(sra + 48)) << kbits) + gca * 8;
    int br0 = colb + srb;      if (br0 > Vm1) br0 = Vm1;
    int br1 = colb + srb + 16; if (br1 > Vm1) br1 = Vm1;
    const unsigned short* Bp0 = B + (((size_t)br0) << kbits) + gcb * 8;
    const unsigned short* Bp1 = B + (((size_t)br1) << kbits) + gcb * 8;

    auto issue = [&](size_t roff, int s, int slot) {
        int koff = s << 5;
        unsigned short* as = Asm + slot * ASTG + wave * 2048;
        unsigned short* bs = Bsm + slot * BSTG + wave * 1024;
        gload16(Ab0 + roff + koff, as);        gload16(Ab1 + roff + koff, as + 512);
        gload16(Ab2 + roff + koff, as + 1024); gload16(Ab3 + roff + koff, as + 1536);
        gload16(Bp0 + koff, bs);               gload16(Bp1 + koff, bs + 512);
    };

    int sw = (fk ^ ((fr >> 1) & 3)) * 8;
    int ra[8], rc[4];
#pragma unroll
    for (int i = 0; i < 8; ++i) ra[i] = (wrow + i * 16 + fr) * 32 + sw;
#pragma unroll
    for (int i = 0; i < 4; ++i) rc[i] = (wcol + i * 16 + fr) * 32 + sw;

    // per-block epilogue constants BEFORE the prologue: the (head-only) bias
    // loads drain here, so the counted-vmcnt pipeline sees a clean queue.
    float ebv[4];
#pragma unroll
    for (int ct = 0; ct < 4; ++ct) {
        int vcol = colb + wcol + ct * 16 + fr;
        ebv[ct] = (vcol < V) ? ((bias != nullptr) ? __expf(bias[vcol]) : 1.0f) : 0.0f;
    }

    size_t roff = ((size_t)(g * 256)) << kbits;
    issue(roff, 0, 0); issue(roff, 1, 1);
    for (int r = g; r < 16; r += 4) {
        int row_base = r * 256;
        floatx4 acc[8][4] = {};
        int sc = 0, si = 2;
        for (int j = 0; j < T; ++j) {
            if (j + 2 < T) { issue(roff, j + 2, si); si = (si == 2) ? 0 : si + 1; }
            int rem = T - 1 - j;
            if (rem >= 2) { WAIT_VM12(); }
            else if (rem == 1) { WAIT_VM6(); }
            else { WAIT_VM0(); }
            WAIT_LGKM();
            __builtin_amdgcn_s_barrier();
            const unsigned short* As = Asm + sc * ASTG;
            const unsigned short* Bs = Bsm + sc * BSTG;
            sc = (sc == 2) ? 0 : sc + 1;
            short8 af[8], bf[4];
#pragma unroll
            for (int i = 0; i < 8; ++i) af[i] = *(const short8*)&As[ra[i]];
#pragma unroll
            for (int i = 0; i < 4; ++i) bf[i] = *(const short8*)&Bs[rc[i]];
#pragma unroll
            for (int rt = 0; rt < 8; ++rt)
#pragma unroll
                for (int ct = 0; ct < 4; ++ct)
                    acc[rt][ct] = __builtin_amdgcn_mfma_f32_16x16x32_bf16(af[rt], bf[ct], acc[rt][ct], 0, 0, 0);
        }
        // fence: every wave's LDS reads of slots are complete after this
        // barrier (each wave lgkm0's first) -> safe to DMA-overwrite slot 0/1.
        WAIT_LGKM();
        __builtin_amdgcn_s_barrier();
        int rn = r + 4;
        bool more = (rn < 16) && (rn * 256 < n);
        if (more) {
            roff = ((size_t)(rn * 256)) << kbits;
            issue(roff, 0, 0); issue(roff, 1, 1);   // next-run prologue hides under epilogue
        }
        // epilogue: per-row sum of exp(acc)*ebv. |logit| < ~6 (xavier) ->
        // max-free sum(exp) is fp32-safe. OOB columns: ebv=0 kills them.
        // Raw barriers only (no __syncthreads): prefetch must stay in flight.
#pragma unroll
        for (int rt = 0; rt < 8; ++rt) {
#pragma unroll
            for (int q = 0; q < 4; ++q) {
                float s = 0.f;
#pragma unroll
                for (int ct = 0; ct < 4; ++ct)
                    s = fmaf(__expf(acc[rt][ct][q]), ebv[ct], s);
                s = row16_sum(s);
                if (fr == 0) cs[wrow + rt * 16 + fk * 4 + q][wave & 1] = s;
            }
        }
        WAIT_LGKM();
        __builtin_amdgcn_s_barrier();
        ps[(size_t)ch * NTOK + row_base + t] = cs[t][0] + cs[t][1];
        if (!more) break;
    }
}

// ---------------- reduce: wave-per-token LSE + label-logit dot + NLL ----------------
// One wave per token (12288 waves / 3072 blocks). 64-lane-parallel partial
// sums + bf16 K-dot for the label logit.
__global__ __launch_bounds__(256)
void reduce_all_k(const float* __restrict__ ps0, const unsigned short* __restrict__ h0,
                  const unsigned short* __restrict__ t0w2, const int* __restrict__ lab0,
                  const int* __restrict__ n0p,
                  const float* __restrict__ ps1, const unsigned short* __restrict__ h1,
                  const unsigned short* __restrict__ t1w2, const int* __restrict__ lab1,
                  const int* __restrict__ n1p,
                  const float* __restrict__ psh, const unsigned short* __restrict__ win,
                  const unsigned short* __restrict__ hw, const int* __restrict__ labh,
                  const float* __restrict__ head_b,
                  float* __restrict__ lossb) {
    __shared__ float part[4];
    int tid = threadIdx.x, lane = tid & 63, w = tid >> 6;
    int wid = blockIdx.x * 4 + w;
    int seg = wid >> 12, p = wid & 4095;
    const float* ps; const unsigned short* A; const unsigned short* B; const int* lab;
    int n, nc, kbits;
    if (seg == 0)      { ps = ps0; A = h0;  B = t0w2; lab = lab0; n = *n0p; nc = 63;  kbits = 10; }
    else if (seg == 1) { ps = ps1; A = h1;  B = t1w2; lab = lab1; n = *n1p; nc = 313; kbits = 8; }
    else               { ps = psh; A = win; B = hw;   lab = labh; n = NTOK; nc = 16;  kbits = 10; }
    float nll = 0.f;
    if (p < n) {                       // wave-uniform (p is per-wave)
        int L = lab[p];
        float S = 0.f;
        for (int c = lane; c < nc; c += 64) S += ps[(size_t)c * NTOK + p];
        int K = 1 << kbits;
        const unsigned short* ar = A + ((size_t)p << kbits);
        const unsigned short* br = B + ((size_t)L << kbits);
        float d = 0.f;
        for (int k = lane * 8; k < K; k += 512) {
            short8 av = *(const short8*)(ar + k);
            short8 bv = *(const short8*)(br + k);
#pragma unroll
            for (int e = 0; e < 8; ++e)
                d = fmaf(bf2f((unsigned short)av[e]), bf2f((unsigned short)bv[e]), d);
        }
#pragma unroll
        for (int off = 1; off < 64; off <<= 1) {
            S += __shfl_xor(S, off, 64);
            d += __shfl_xor(d, off, 64);
        }
        if (lane == 0) {
            float bias = (seg == 2) ? head_b[L] : 0.f;
            nll = logf(S) - d - bias;
        }
    }
    if (lane == 0) part[w] = nll;
    __syncthreads();
    if (tid == 0) atomicAdd(&lossb[blockIdx.x & 63], part[0] + part[1] + part[2] + part[3]);
}

__global__ void final_k(const float* __restrict__ lossb, float* __restrict__ out) {
    float v = lossb[threadIdx.x];
    for (int off = 32; off; off >>= 1) v += __shfl_down(v, off, 64);
    if (threadIdx.x == 0) out[0] = v * (1.0f / 4096.0f);
}

extern "C" void kernel_launch(void* const* d_in, const int* in_sizes, int n_in,
                              void* d_out, int out_size, void* d_ws, size_t ws_size,
                              hipStream_t stream) {
    const float* w_in   = (const float*)d_in[0];
    const int*   target = (const int*)d_in[1];
    const float* head_w = (const float*)d_in[2];
    const float* head_b = (const float*)d_in[3];
    const float* t0w1   = (const float*)d_in[4];
    const float* t0w2   = (const float*)d_in[5];
    const float* t1w1   = (const float*)d_in[6];
    const float* t1w2   = (const float*)d_in[7];
    float* out = (float*)d_out;

    char* wsb = (char*)d_ws;
    size_t o = 0;
    auto alloc = [&](size_t bytes) -> void* {
        void* p = wsb + o;
        o += (bytes + 255) & ~(size_t)255;
        return p;
    };
    float* lossb = (float*)alloc(64 * 4);   // 64 partial-loss buckets (offset 0)
    int* n0 = (int*)alloc(4);               // offset 256
    int* n1 = (int*)alloc(4);               // offset 512
    int* idx0 = (int*)alloc(NTOK * 4);
    int* lab0 = (int*)alloc(NTOK * 4);
    int* idx1 = (int*)alloc(NTOK * 4);
    int* lab1 = (int*)alloc(NTOK * 4);
    int* labh = (int*)alloc(NTOK * 4);

    const int SZ_WIN = NTOK * 1024, SZ_HW = 2002 * 1024, SZ_T0W1 = 1024 * 1024,
              SZ_T0W2 = 8000 * 1024, SZ_T1W1 = 256 * 1024, SZ_T1W2 = 40000 * 256;
    unsigned short* win_bf  = (unsigned short*)alloc((size_t)SZ_WIN * 2);
    unsigned short* hw_bf   = (unsigned short*)alloc((size_t)SZ_HW * 2);
    unsigned short* t0w1_bf = (unsigned short*)alloc((size_t)SZ_T0W1 * 2);
    unsigned short* t0w2_bf = (unsigned short*)alloc((size_t)SZ_T0W2 * 2);
    unsigned short* t1w1_bf = (unsigned short*)alloc((size_t)SZ_T1W1 * 2);
    unsigned short* t1w2_bf = (unsigned short*)alloc((size_t)SZ_T1W2 * 2);
    unsigned short* h0 = (unsigned short*)alloc((size_t)NTOK * 1024 * 2);
    unsigned short* h1 = (unsigned short*)alloc((size_t)NTOK * 256 * 2);

    const int NC0 = 63, NC1 = 313, NCH = 16;   // chunks per segment (per-chunk partials)
    float* ps0 = (float*)alloc((size_t)NC0 * NTOK * 4);
    float* ps1 = (float*)alloc((size_t)NC1 * NTOK * 4);
    float* psh = (float*)alloc((size_t)NCH * NTOK * 4);

    dim3 blk(256);
    hipMemsetAsync(d_ws, 0, 768, stream);   // zero lossb, n0, n1

    // prep: compact (16 blocks) + cvt of win/t0w1/t1w1 (1376 blocks)
    prep_k<<<16 + 1376, blk, 0, stream>>>(
        w_in, win_bf, t0w1, t0w1_bf, t1w1, t1w1_bf,
        target, idx0, lab0, n0, idx1, lab1, n1, labh);

    // hgemm (320 blocks, ~100 active) overlapped with cvt of hw/t0w2/t1w2 (1280 blocks)
    hgemm_cvt_k<<<320 + 1280, blk, 0, stream>>>(
        win_bf, t0w1_bf, h0, idx0, n0, t1w1_bf, h1, idx1, n1,
        head_w, hw_bf, t0w2, t0w2_bf, t1w2, t1w2_bf);

    // panel-persistent ce: (16 + 63 + 313) panels x 4 g-blocks = 1568 blocks
    ce_all_k<<<392 * 4, blk, 0, stream>>>(
        h1, t1w2_bf, n1, ps1,
        h0, t0w2_bf, n0, ps0,
        win_bf, hw_bf, head_b, psh);

    // one wave per token: 3*4096 waves, 4 waves/block -> 3072 blocks
    reduce_all_k<<<3 * NTOK / 4, blk, 0, stream>>>(
        ps0, h0, t0w2_bf, lab0, n0,
        ps1, h1, t1w2_bf, lab1, n1,
        psh, win_bf, hw_bf, labh, head_b, lossb);

    final_k<<<1, 64, 0, stream>>>(lossb, out);
}

// Round 5
// 297.235 us; speedup vs baseline: 1.0465x; 1.0465x over previous
//
#include <hip/hip_runtime.h>
#include <math.h>

#define NTOK 4096

typedef __attribute__((ext_vector_type(8))) short short8;
typedef __attribute__((ext_vector_type(4))) float floatx4;

static __device__ __forceinline__ unsigned short f2bf(float f) {
    unsigned int u = __float_as_uint(f);
    unsigned int r = (u + 0x7fffu + ((u >> 16) & 1u)) >> 16;
    return (unsigned short)r;
}

static __device__ __forceinline__ float bf2f(unsigned short s) {
    return __uint_as_float((unsigned)s << 16);
}

// async global->LDS, 16B per lane. LDS dest = wave-uniform base + lane*16.
static __device__ __forceinline__ void gload16(const void* g, void* l) {
    __builtin_amdgcn_global_load_lds(
        (const __attribute__((address_space(1))) void*)g,
        (__attribute__((address_space(3))) void*)(unsigned int)(unsigned long long)l,
        16, 0, 0);
}

// 16-lane (DPP row) sum butterfly: all lanes of each 16-lane group end with the
// group sum. VALU-only -- no LDS-pipe contention with main-loop ds_read_b128.
static __device__ __forceinline__ float row16_sum(float x) {
    x += __int_as_float(__builtin_amdgcn_update_dpp(0, __float_as_int(x), 0xB1, 0xF, 0xF, true));  // quad_perm xor1
    x += __int_as_float(__builtin_amdgcn_update_dpp(0, __float_as_int(x), 0x4E, 0xF, 0xF, true));  // quad_perm xor2
    x += __int_as_float(__builtin_amdgcn_update_dpp(0, __float_as_int(x), 0x141, 0xF, 0xF, true)); // row_half_mirror
    x += __int_as_float(__builtin_amdgcn_update_dpp(0, __float_as_int(x), 0x140, 0xF, 0xF, true)); // row_mirror
    return x;
}

#define WAIT_VM12() asm volatile("s_waitcnt vmcnt(12)" ::: "memory")
#define WAIT_VM8()  asm volatile("s_waitcnt vmcnt(8)" ::: "memory")
#define WAIT_VM6()  asm volatile("s_waitcnt vmcnt(6)" ::: "memory")
#define WAIT_VM4()  asm volatile("s_waitcnt vmcnt(4)" ::: "memory")
#define WAIT_VM0()  asm volatile("s_waitcnt vmcnt(0)" ::: "memory")
#define WAIT_LGKM() asm volatile("s_waitcnt lgkmcnt(0)" ::: "memory")

// ce stage: A 256x32 (16KB) + B 128x32 (8KB); 3 stages
#define ASTG 8192   // shorts per A stage
#define BSTG 4096   // shorts per B stage
// hgemm stage: 128x32 A and B (8KB each)
#define STG 4096

// ---------------- prep: compact (blocks 0..15) + cvt of win/t0w1/t1w1 ----------------
// flat-indexed cvt: block allocation proportional to array size (no per-array tail).
__global__ __launch_bounds__(256)
void prep_k(const float* __restrict__ w_in, unsigned short* __restrict__ win_bf,
            const float* __restrict__ t0w1, unsigned short* __restrict__ t0w1_bf,
            const float* __restrict__ t1w1, unsigned short* __restrict__ t1w1_bf,
            const int* __restrict__ target,
            int* __restrict__ idx0, int* __restrict__ lab0, int* __restrict__ n0,
            int* __restrict__ idx1, int* __restrict__ lab1, int* __restrict__ n1,
            int* __restrict__ labh) {
    int bid = blockIdx.x;
    if (bid < 16) {
        int i = bid * 256 + threadIdx.x;   // 4096 threads exactly, wave-uniform
        int t = target[i];
        int lane = threadIdx.x & 63;
        unsigned long long below = (1ull << lane) - 1ull;
        bool m0 = (t >= 2000) && (t < 10000);
        bool m1 = (t >= 10000);
        unsigned long long b0 = __ballot(m0);
        unsigned long long b1 = __ballot(m1);
        int ft = t;
        // wave-aggregated compaction: 1 atomic per wave per counter.
        if (m0) {
            int ldr = __ffsll((long long)b0) - 1;
            int base = 0;
            if (lane == ldr) base = atomicAdd(n0, __popcll(b0));
            base = __shfl(base, ldr, 64);
            int p = base + __popcll(b0 & below);
            idx0[p] = i; lab0[p] = t - 2000; ft = 2000;
        } else if (m1) {
            int ldr = __ffsll((long long)b1) - 1;
            int base = 0;
            if (lane == ldr) base = atomicAdd(n1, __popcll(b1));
            base = __shfl(base, ldr, 64);
            int p = base + __popcll(b1 & below);
            idx1[p] = i; lab1[p] = t - 10000; ft = 2001;
        }
        labh[i] = ft;
        return;
    }
    // cvt: flat float4 index over [w_in | t0w1 | t1w1]
    const int E0 = 4194304, E1 = E0 + 1048576, TOT = E1 + 262144;   // floats
    int gi = (bid - 16) * 256 + threadIdx.x;
    int stride = (gridDim.x - 16) * 256;
    for (int i4 = gi; i4 * 4 < TOT; i4 += stride) {
        int i = i4 * 4;
        const float* s; unsigned short* d; int off;
        if (i < E0)      { s = w_in;  d = win_bf;  off = i; }
        else if (i < E1) { s = t0w1; d = t0w1_bf; off = i - E0; }
        else             { s = t1w1; d = t1w1_bf; off = i - E1; }
        float4 v = *(const float4*)(s + off);
        ushort4 o;
        o.x = f2bf(v.x); o.y = f2bf(v.y); o.z = f2bf(v.z); o.w = f2bf(v.w);
        *(ushort4*)(d + off) = o;
    }
}

// ---------------- merged gathered h-GEMM (blocks 0..319) + cvt of hw/t0w2/t1w2 ----------------
// hgemm only has ~100 active blocks (>60% of CUs idle) -- the cvt blocks fill
// the rest of the machine, overlapping 102MB of pure-BW work with the GEMM.
__global__ __launch_bounds__(256)
void hgemm_cvt_k(const unsigned short* __restrict__ win,
                 const unsigned short* __restrict__ t0w1, unsigned short* __restrict__ h0o,
                 const int* __restrict__ idx0, const int* __restrict__ n0p,
                 const unsigned short* __restrict__ t1w1, unsigned short* __restrict__ h1o,
                 const int* __restrict__ idx1, const int* __restrict__ n1p,
                 const float* __restrict__ head_w, unsigned short* __restrict__ hw_bf,
                 const float* __restrict__ t0w2, unsigned short* __restrict__ t0w2_bf,
                 const float* __restrict__ t1w2, unsigned short* __restrict__ t1w2_bf) {
    __shared__ unsigned short Asm[3 * STG];
    __shared__ unsigned short Bsm[3 * STG];
    __shared__ int sidx[128];
    int bid = blockIdx.x;
    if (bid >= 320) {
        const int E0 = 2050048, E1 = E0 + 8192000, TOT = E1 + 10240000;   // floats
        int gi = (bid - 320) * 256 + threadIdx.x;
        int stride = (gridDim.x - 320) * 256;
        for (int i4 = gi; i4 * 4 < TOT; i4 += stride) {
            int i = i4 * 4;
            const float* s; unsigned short* d; int off;
            if (i < E0)      { s = head_w; d = hw_bf;   off = i; }
            else if (i < E1) { s = t0w2;  d = t0w2_bf; off = i - E0; }
            else             { s = t1w2;  d = t1w2_bf; off = i - E1; }
            float4 v = *(const float4*)(s + off);
            ushort4 o;
            o.x = f2bf(v.x); o.y = f2bf(v.y); o.z = f2bf(v.z); o.w = f2bf(v.w);
            *(ushort4*)(d + off) = o;
        }
        return;
    }
    const unsigned short* B; unsigned short* H; const int* idx; int n, P, rb, cb;
    if (bid < 256) { rb = bid >> 3; cb = bid & 7; B = t0w1; H = h0o; idx = idx0; n = *n0p; P = 1024; }
    else { int b = bid - 256; rb = b >> 1; cb = b & 1; B = t1w1; H = h1o; idx = idx1; n = *n1p; P = 256; }
    const int K = 1024, T = 32;
    int row_base = rb * 128;
    if (row_base >= n) return;
    int col_base = cb * 128;
    int t = threadIdx.x;
    int wave = t >> 6, lane = t & 63;
    int wrow = (wave >> 1) * 64, wcol = (wave & 1) * 64;
    int fr = lane & 15, fk = lane >> 4;

    if (t < 128) { int r = row_base + t; sidx[t] = idx[r < n ? r : n - 1]; }
    __syncthreads();   // drains vmcnt: clean slate before manual pipeline (gather needs sidx)

    int sr0 = wave * 32 + (lane >> 2);
    int sr1 = sr0 + 16;
    int c0l = lane & 3;
    int gc0 = c0l ^ ((sr0 >> 1) & 3);
    int gc1 = c0l ^ ((sr1 >> 1) & 3);
    const unsigned short* Ab0 = win + (size_t)sidx[sr0] * K + gc0 * 8;
    const unsigned short* Ab1 = win + (size_t)sidx[sr1] * K + gc1 * 8;
    const unsigned short* Bb0 = B + (size_t)(col_base + sr0) * K + gc0 * 8;
    const unsigned short* Bb1 = B + (size_t)(col_base + sr1) * K + gc1 * 8;

    auto issue = [&](int s, int slot) {
        int koff = s << 5;
        unsigned short* as = Asm + slot * STG + wave * 1024;
        unsigned short* bs = Bsm + slot * STG + wave * 1024;
        gload16(Ab0 + koff, as); gload16(Ab1 + koff, as + 512);
        gload16(Bb0 + koff, bs); gload16(Bb1 + koff, bs + 512);
    };

    int sw = (fk ^ ((fr >> 1) & 3)) * 8;
    int ra[4], rc[4];
#pragma unroll
    for (int i = 0; i < 4; ++i) {
        ra[i] = (wrow + i * 16 + fr) * 32 + sw;
        rc[i] = (wcol + i * 16 + fr) * 32 + sw;
    }

    issue(0, 0); issue(1, 1);
    floatx4 acc[4][4] = {};
    int sc = 0, si = 2;
    for (int j = 0; j < T; ++j) {
        if (j + 2 < T) { issue(j + 2, si); si = (si == 2) ? 0 : si + 1; }
        int rem = T - 1 - j;
        if (rem >= 2) { WAIT_VM8(); }
        else if (rem == 1) { WAIT_VM4(); }
        else { WAIT_VM0(); }
        WAIT_LGKM();
        __builtin_amdgcn_s_barrier();
        const unsigned short* As = Asm + sc * STG;
        const unsigned short* Bs = Bsm + sc * STG;
        sc = (sc == 2) ? 0 : sc + 1;
        short8 af[4], bf[4];
#pragma unroll
        for (int i = 0; i < 4; ++i) af[i] = *(const short8*)&As[ra[i]];
#pragma unroll
        for (int i = 0; i < 4; ++i) bf[i] = *(const short8*)&Bs[rc[i]];
#pragma unroll
        for (int rt = 0; rt < 4; ++rt)
#pragma unroll
            for (int ct = 0; ct < 4; ++ct)
                acc[rt][ct] = __builtin_amdgcn_mfma_f32_16x16x32_bf16(af[rt], bf[ct], acc[rt][ct], 0, 0, 0);
    }
#pragma unroll
    for (int rt = 0; rt < 4; ++rt)
#pragma unroll
        for (int r = 0; r < 4; ++r) {
            int row = row_base + wrow + rt * 16 + fk * 4 + r;
#pragma unroll
            for (int ct = 0; ct < 4; ++ct) {
                int col = col_base + wcol + ct * 16 + fr;
                H[(size_t)row * P + col] = f2bf(acc[rt][ct][r]);
            }
        }
}

// ---------------- CE: 256x128 tiles, block-per-tile + XCD panel affinity ----------------
// Round-5: round-3 body (one tile per block, full TLP: 6272 blocks) with a
// bid->(panel,rb) mapping that gives L2 panel reuse WITHOUT losing parallelism
// (round-4 lesson: FETCH halved but TLP loss cost more).
//   bid = (p>>3)<<7 | rb<<3 | (p&7)   (p = panel 0..391, rb = 0..15)
// -> all 16 rb-blocks of panel p share bid%8 (same XCD under round-robin
// dispatch heuristic) and sit within 512 consecutive bids (near-co-resident),
// so the 64-256KB B panel is L2-hot after its first reader. Per-XCD resident
// panel set ~4 panels <= 1MB << 4MB L2. Speed-only heuristic.
// Panels: p<16 head (V=2002,K=1024,T=32, heaviest -> lowest bids, dispatched
// first); p<79 tail0 (V=8000,K=1024,T=32); else tail1 (V=40000,K=256,T=8).
// 3-stage counted pipeline, issue-BEFORE-wait, waits 12/6/0. ebv (bias) loads
// issue before the prologue; the one-time vm-queue bubble drains within the
// first two counted waits (oldest-N semantics) regardless of load order.
__global__ __launch_bounds__(256, 2)
void ce_all_k(const unsigned short* __restrict__ h1, const unsigned short* __restrict__ t1w2,
              const int* __restrict__ n1p, float* __restrict__ ps1,
              const unsigned short* __restrict__ h0, const unsigned short* __restrict__ t0w2,
              const int* __restrict__ n0p, float* __restrict__ ps0,
              const unsigned short* __restrict__ win, const unsigned short* __restrict__ hw,
              const float* __restrict__ head_b, float* __restrict__ psh) {
    __shared__ unsigned short Asm[3 * ASTG];
    __shared__ unsigned short Bsm[3 * BSTG];
    __shared__ float cs[256][2];
    int bid = blockIdx.x;
    int pan = ((bid >> 7) << 3) | (bid & 7);   // 0..391
    int rb  = (bid >> 3) & 15;
    const unsigned short* A; const unsigned short* B; const float* bias = nullptr;
    int n, V, kbits, T, ch;
    float* ps;
    if (pan < 16) {
        ch = pan;      A = win; B = hw;   n = NTOK; V = 2002;  kbits = 10; T = 32; ps = psh; bias = head_b;
    } else if (pan < 79) {
        ch = pan - 16; A = h0;  B = t0w2; n = *n0p; V = 8000;  kbits = 10; T = 32; ps = ps0;
    } else {
        ch = pan - 79; A = h1;  B = t1w2; n = *n1p; V = 40000; kbits = 8;  T = 8;  ps = ps1;
    }
    int row_base = rb * 256;
    if (row_base >= n) return;
    int colb = ch << 7;
    int Vm1 = V - 1;
    int t = threadIdx.x;
    int wave = t >> 6, lane = t & 63;
    int wrow = (wave >> 1) * 128, wcol = (wave & 1) * 64;
    int fr = lane & 15, fk = lane >> 4;

    // staging: A 256x32 (4 instr/wave, 16-row steps), B 128x32 (2 instr/wave)
    int sra = wave * 64 + (lane >> 2);
    int srb = wave * 32 + (lane >> 2);
    int c0l = lane & 3;
    int gca = c0l ^ ((sra >> 1) & 3);   // +16 row steps preserve (r>>1)&3
    int gcb = c0l ^ ((srb >> 1) & 3);
    const unsigned short* Ap0 = A + (((size_t)(row_base + sra)) << kbits) + gca * 8;
    const unsigned short* Ap1 = A + (((size_t)(row_base + sra + 16)) << kbits) + gca * 8;
    const unsigned short* Ap2 = A + (((size_t)(row_base + sra + 32)) << kbits) + gca * 8;
    const unsigned short* Ap3 = A + (((size_t)(row_base + sra + 48)) << kbits) + gca * 8;
    int br0 = colb + srb;      if (br0 > Vm1) br0 = Vm1;
    int br1 = colb + srb + 16; if (br1 > Vm1) br1 = Vm1;
    const unsigned short* Bp0 = B + (((size_t)br0) << kbits) + gcb * 8;
    const unsigned short* Bp1 = B + (((size_t)br1) << kbits) + gcb * 8;

    auto issue = [&](int s, int slot) {
        int koff = s << 5;
        unsigned short* as = Asm + slot * ASTG + wave * 2048;
        unsigned short* bs = Bsm + slot * BSTG + wave * 1024;
        gload16(Ap0 + koff, as);        gload16(Ap1 + koff, as + 512);
        gload16(Ap2 + koff, as + 1024); gload16(Ap3 + koff, as + 1536);
        gload16(Bp0 + koff, bs);        gload16(Bp1 + koff, bs + 512);
    };

    int sw = (fk ^ ((fr >> 1) & 3)) * 8;
    int ra[8], rc[4];
#pragma unroll
    for (int i = 0; i < 8; ++i) ra[i] = (wrow + i * 16 + fr) * 32 + sw;
#pragma unroll
    for (int i = 0; i < 4; ++i) rc[i] = (wcol + i * 16 + fr) * 32 + sw;

    // epilogue constants before the prologue: bias loads fill-overlap the
    // pipeline; the bubble drains at the first two counted waits.
    float ebv[4];
#pragma unroll
    for (int ct = 0; ct < 4; ++ct) {
        int vcol = colb + wcol + ct * 16 + fr;
        ebv[ct] = (vcol < V) ? ((bias != nullptr) ? __expf(bias[vcol]) : 1.0f) : 0.0f;
    }

    issue(0, 0); issue(1, 1);
    floatx4 acc[8][4] = {};
    int sc = 0, si = 2;
    for (int j = 0; j < T; ++j) {
        if (j + 2 < T) { issue(j + 2, si); si = (si == 2) ? 0 : si + 1; }
        int rem = T - 1 - j;
        if (rem >= 2) { WAIT_VM12(); }
        else if (rem == 1) { WAIT_VM6(); }
        else { WAIT_VM0(); }
        WAIT_LGKM();
        __builtin_amdgcn_s_barrier();
        const unsigned short* As = Asm + sc * ASTG;
        const unsigned short* Bs = Bsm + sc * BSTG;
        sc = (sc == 2) ? 0 : sc + 1;
        short8 af[8], bf[4];
#pragma unroll
        for (int i = 0; i < 8; ++i) af[i] = *(const short8*)&As[ra[i]];
#pragma unroll
        for (int i = 0; i < 4; ++i) bf[i] = *(const short8*)&Bs[rc[i]];
#pragma unroll
        for (int rt = 0; rt < 8; ++rt)
#pragma unroll
            for (int ct = 0; ct < 4; ++ct)
                acc[rt][ct] = __builtin_amdgcn_mfma_f32_16x16x32_bf16(af[rt], bf[ct], acc[rt][ct], 0, 0, 0);
    }

    // epilogue: per-row sum of exp(acc)*ebv. |logit| < ~6 (xavier) -> max-free
    // sum(exp) is fp32-safe. OOB columns: ebv=0 kills them (exp(acc) finite).
#pragma unroll
    for (int rt = 0; rt < 8; ++rt) {
#pragma unroll
        for (int q = 0; q < 4; ++q) {
            float s = 0.f;
#pragma unroll
            for (int ct = 0; ct < 4; ++ct)
                s = fmaf(__expf(acc[rt][ct][q]), ebv[ct], s);
            s = row16_sum(s);
            if (fr == 0) cs[wrow + rt * 16 + fk * 4 + q][wave & 1] = s;
        }
    }
    __syncthreads();
    ps[(size_t)ch * NTOK + row_base + t] = cs[t][0] + cs[t][1];
}

// ---------------- reduce: wave-per-token LSE + label-logit dot + NLL ----------------
// One wave per token (12288 waves / 3072 blocks). 64-lane-parallel partial
// sums + bf16 K-dot for the label logit.
__global__ __launch_bounds__(256)
void reduce_all_k(const float* __restrict__ ps0, const unsigned short* __restrict__ h0,
                  const unsigned short* __restrict__ t0w2, const int* __restrict__ lab0,
                  const int* __restrict__ n0p,
                  const float* __restrict__ ps1, const unsigned short* __restrict__ h1,
                  const unsigned short* __restrict__ t1w2, const int* __restrict__ lab1,
                  const int* __restrict__ n1p,
                  const float* __restrict__ psh, const unsigned short* __restrict__ win,
                  const unsigned short* __restrict__ hw, const int* __restrict__ labh,
                  const float* __restrict__ head_b,
                  float* __restrict__ lossb) {
    __shared__ float part[4];
    int tid = threadIdx.x, lane = tid & 63, w = tid >> 6;
    int wid = blockIdx.x * 4 + w;
    int seg = wid >> 12, p = wid & 4095;
    const float* ps; const unsigned short* A; const unsigned short* B; const int* lab;
    int n, nc, kbits;
    if (seg == 0)      { ps = ps0; A = h0;  B = t0w2; lab = lab0; n = *n0p; nc = 63;  kbits = 10; }
    else if (seg == 1) { ps = ps1; A = h1;  B = t1w2; lab = lab1; n = *n1p; nc = 313; kbits = 8; }
    else               { ps = psh; A = win; B = hw;   lab = labh; n = NTOK; nc = 16;  kbits = 10; }
    float nll = 0.f;
    if (p < n) {                       // wave-uniform (p is per-wave)
        int L = lab[p];
        float S = 0.f;
        for (int c = lane; c < nc; c += 64) S += ps[(size_t)c * NTOK + p];
        int K = 1 << kbits;
        const unsigned short* ar = A + ((size_t)p << kbits);
        const unsigned short* br = B + ((size_t)L << kbits);
        float d = 0.f;
        for (int k = lane * 8; k < K; k += 512) {
            short8 av = *(const short8*)(ar + k);
            short8 bv = *(const short8*)(br + k);
#pragma unroll
            for (int e = 0; e < 8; ++e)
                d = fmaf(bf2f((unsigned short)av[e]), bf2f((unsigned short)bv[e]), d);
        }
#pragma unroll
        for (int off = 1; off < 64; off <<= 1) {
            S += __shfl_xor(S, off, 64);
            d += __shfl_xor(d, off, 64);
        }
        if (lane == 0) {
            float bias = (seg == 2) ? head_b[L] : 0.f;
            nll = logf(S) - d - bias;
        }
    }
    if (lane == 0) part[w] = nll;
    __syncthreads();
    if (tid == 0) atomicAdd(&lossb[blockIdx.x & 63], part[0] + part[1] + part[2] + part[3]);
}

__global__ void final_k(const float* __restrict__ lossb, float* __restrict__ out) {
    float v = lossb[threadIdx.x];
    for (int off = 32; off; off >>= 1) v += __shfl_down(v, off, 64);
    if (threadIdx.x == 0) out[0] = v * (1.0f / 4096.0f);
}

extern "C" void kernel_launch(void* const* d_in, const int* in_sizes, int n_in,
                              void* d_out, int out_size, void* d_ws, size_t ws_size,
                              hipStream_t stream) {
    const float* w_in   = (const float*)d_in[0];
    const int*   target = (const int*)d_in[1];
    const float* head_w = (const float*)d_in[2];
    const float* head_b = (const float*)d_in[3];
    const float* t0w1   = (const float*)d_in[4];
    const float* t0w2   = (const float*)d_in[5];
    const float* t1w1   = (const float*)d_in[6];
    const float* t1w2   = (const float*)d_in[7];
    float* out = (float*)d_out;

    char* wsb = (char*)d_ws;
    size_t o = 0;
    auto alloc = [&](size_t bytes) -> void* {
        void* p = wsb + o;
        o += (bytes + 255) & ~(size_t)255;
        return p;
    };
    float* lossb = (float*)alloc(64 * 4);   // 64 partial-loss buckets (offset 0)
    int* n0 = (int*)alloc(4);               // offset 256
    int* n1 = (int*)alloc(4);               // offset 512
    int* idx0 = (int*)alloc(NTOK * 4);
    int* lab0 = (int*)alloc(NTOK * 4);
    int* idx1 = (int*)alloc(NTOK * 4);
    int* lab1 = (int*)alloc(NTOK * 4);
    int* labh = (int*)alloc(NTOK * 4);

    const int SZ_WIN = NTOK * 1024, SZ_HW = 2002 * 1024, SZ_T0W1 = 1024 * 1024,
              SZ_T0W2 = 8000 * 1024, SZ_T1W1 = 256 * 1024, SZ_T1W2 = 40000 * 256;
    unsigned short* win_bf  = (unsigned short*)alloc((size_t)SZ_WIN * 2);
    unsigned short* hw_bf   = (unsigned short*)alloc((size_t)SZ_HW * 2);
    unsigned short* t0w1_bf = (unsigned short*)alloc((size_t)SZ_T0W1 * 2);
    unsigned short* t0w2_bf = (unsigned short*)alloc((size_t)SZ_T0W2 * 2);
    unsigned short* t1w1_bf = (unsigned short*)alloc((size_t)SZ_T1W1 * 2);
    unsigned short* t1w2_bf = (unsigned short*)alloc((size_t)SZ_T1W2 * 2);
    unsigned short* h0 = (unsigned short*)alloc((size_t)NTOK * 1024 * 2);
    unsigned short* h1 = (unsigned short*)alloc((size_t)NTOK * 256 * 2);

    const int NC0 = 63, NC1 = 313, NCH = 16;   // chunks per segment (per-chunk partials)
    float* ps0 = (float*)alloc((size_t)NC0 * NTOK * 4);
    float* ps1 = (float*)alloc((size_t)NC1 * NTOK * 4);
    float* psh = (float*)alloc((size_t)NCH * NTOK * 4);

    dim3 blk(256);
    hipMemsetAsync(d_ws, 0, 768, stream);   // zero lossb, n0, n1

    // prep: compact (16 blocks) + cvt of win/t0w1/t1w1 (1376 blocks)
    prep_k<<<16 + 1376, blk, 0, stream>>>(
        w_in, win_bf, t0w1, t0w1_bf, t1w1, t1w1_bf,
        target, idx0, lab0, n0, idx1, lab1, n1, labh);

    // hgemm (320 blocks, ~100 active) overlapped with cvt of hw/t0w2/t1w2 (1280 blocks)
    hgemm_cvt_k<<<320 + 1280, blk, 0, stream>>>(
        win_bf, t0w1_bf, h0, idx0, n0, t1w1_bf, h1, idx1, n1,
        head_w, hw_bf, t0w2, t0w2_bf, t1w2, t1w2_bf);

    // block-per-tile ce with XCD panel affinity: 392 panels x 16 rb = 6272
    ce_all_k<<<392 * 16, blk, 0, stream>>>(
        h1, t1w2_bf, n1, ps1,
        h0, t0w2_bf, n0, ps0,
        win_bf, hw_bf, head_b, psh);

    // one wave per token: 3*4096 waves, 4 waves/block -> 3072 blocks
    reduce_all_k<<<3 * NTOK / 4, blk, 0, stream>>>(
        ps0, h0, t0w2_bf, lab0, n0,
        ps1, h1, t1w2_bf, lab1, n1,
        psh, win_bf, hw_bf, labh, head_b, lossb);

    final_k<<<1, 64, 0, stream>>>(lossb, out);
}

// Round 6
// 290.317 us; speedup vs baseline: 1.0714x; 1.0238x over previous
//
#include <hip/hip_runtime.h>
#include <math.h>

#define NTOK 4096

typedef __attribute__((ext_vector_type(8))) short short8;
typedef __attribute__((ext_vector_type(4))) float floatx4;

static __device__ __forceinline__ unsigned short f2bf(float f) {
    unsigned int u = __float_as_uint(f);
    unsigned int r = (u + 0x7fffu + ((u >> 16) & 1u)) >> 16;
    return (unsigned short)r;
}

static __device__ __forceinline__ float bf2f(unsigned short s) {
    return __uint_as_float((unsigned)s << 16);
}

// async global->LDS, 16B per lane. LDS dest = wave-uniform base + lane*16.
static __device__ __forceinline__ void gload16(const void* g, void* l) {
    __builtin_amdgcn_global_load_lds(
        (const __attribute__((address_space(1))) void*)g,
        (__attribute__((address_space(3))) void*)(unsigned int)(unsigned long long)l,
        16, 0, 0);
}

// 16-lane (DPP row) sum butterfly: all lanes of each 16-lane group end with the
// group sum. VALU-only -- no LDS-pipe contention with main-loop ds_read_b128.
static __device__ __forceinline__ float row16_sum(float x) {
    x += __int_as_float(__builtin_amdgcn_update_dpp(0, __float_as_int(x), 0xB1, 0xF, 0xF, true));  // quad_perm xor1
    x += __int_as_float(__builtin_amdgcn_update_dpp(0, __float_as_int(x), 0x4E, 0xF, 0xF, true));  // quad_perm xor2
    x += __int_as_float(__builtin_amdgcn_update_dpp(0, __float_as_int(x), 0x141, 0xF, 0xF, true)); // row_half_mirror
    x += __int_as_float(__builtin_amdgcn_update_dpp(0, __float_as_int(x), 0x140, 0xF, 0xF, true)); // row_mirror
    return x;
}

#define WAIT_VM12() asm volatile("s_waitcnt vmcnt(12)" ::: "memory")
#define WAIT_VM8()  asm volatile("s_waitcnt vmcnt(8)" ::: "memory")
#define WAIT_VM6()  asm volatile("s_waitcnt vmcnt(6)" ::: "memory")
#define WAIT_VM4()  asm volatile("s_waitcnt vmcnt(4)" ::: "memory")
#define WAIT_VM0()  asm volatile("s_waitcnt vmcnt(0)" ::: "memory")
#define WAIT_LGKM() asm volatile("s_waitcnt lgkmcnt(0)" ::: "memory")

// ce stage: A 256x32 (16KB) + B 128x32 (8KB); 3 stages
#define ASTG 8192   // shorts per A stage
#define BSTG 4096   // shorts per B stage
// hgemm stage: 128x32 A and B (8KB each)
#define STG 4096

// ---------------- shared CE tile body (round-3 proven: 123us config) ----------------
// 256x128 tile, 3-stage counted pipeline, issue-BEFORE-wait, waits 12/6/0,
// ebv/bias resolved in the epilogue (round-3 placement). |logit| < ~6 (xavier)
// -> max-free sum(exp) is fp32-safe; OOB columns killed via ebv=0.
static __device__ __forceinline__ void ce_tile(
    const unsigned short* __restrict__ A, const unsigned short* __restrict__ B,
    const float* __restrict__ bias, int n, int V, int kbits, int T,
    int rb, int ch, float* __restrict__ ps,
    unsigned short* Asm, unsigned short* Bsm, float (*cs)[2]) {
    int row_base = rb * 256;
    if (row_base >= n) return;
    int colb = ch << 7;
    int Vm1 = V - 1;
    int t = threadIdx.x;
    int wave = t >> 6, lane = t & 63;
    int wrow = (wave >> 1) * 128, wcol = (wave & 1) * 64;
    int fr = lane & 15, fk = lane >> 4;

    // staging: A 256x32 (4 instr/wave, 16-row steps), B 128x32 (2 instr/wave)
    int sra = wave * 64 + (lane >> 2);
    int srb = wave * 32 + (lane >> 2);
    int c0l = lane & 3;
    int gca = c0l ^ ((sra >> 1) & 3);   // +16 row steps preserve (r>>1)&3
    int gcb = c0l ^ ((srb >> 1) & 3);
    const unsigned short* Ap0 = A + (((size_t)(row_base + sra)) << kbits) + gca * 8;
    const unsigned short* Ap1 = A + (((size_t)(row_base + sra + 16)) << kbits) + gca * 8;
    const unsigned short* Ap2 = A + (((size_t)(row_base + sra + 32)) << kbits) + gca * 8;
    const unsigned short* Ap3 = A + (((size_t)(row_base + sra + 48)) << kbits) + gca * 8;
    int br0 = colb + srb;      if (br0 > Vm1) br0 = Vm1;
    int br1 = colb + srb + 16; if (br1 > Vm1) br1 = Vm1;
    const unsigned short* Bp0 = B + (((size_t)br0) << kbits) + gcb * 8;
    const unsigned short* Bp1 = B + (((size_t)br1) << kbits) + gcb * 8;

    auto issue = [&](int s, int slot) {
        int koff = s << 5;
        unsigned short* as = Asm + slot * ASTG + wave * 2048;
        unsigned short* bs = Bsm + slot * BSTG + wave * 1024;
        gload16(Ap0 + koff, as);        gload16(Ap1 + koff, as + 512);
        gload16(Ap2 + koff, as + 1024); gload16(Ap3 + koff, as + 1536);
        gload16(Bp0 + koff, bs);        gload16(Bp1 + koff, bs + 512);
    };

    int sw = (fk ^ ((fr >> 1) & 3)) * 8;
    int ra[8], rc[4];
#pragma unroll
    for (int i = 0; i < 8; ++i) ra[i] = (wrow + i * 16 + fr) * 32 + sw;
#pragma unroll
    for (int i = 0; i < 4; ++i) rc[i] = (wcol + i * 16 + fr) * 32 + sw;

    issue(0, 0); issue(1, 1);
    floatx4 acc[8][4] = {};
    int sc = 0, si = 2;
    for (int j = 0; j < T; ++j) {
        if (j + 2 < T) { issue(j + 2, si); si = (si == 2) ? 0 : si + 1; }
        int rem = T - 1 - j;
        if (rem >= 2) { WAIT_VM12(); }
        else if (rem == 1) { WAIT_VM6(); }
        else { WAIT_VM0(); }
        WAIT_LGKM();
        __builtin_amdgcn_s_barrier();
        const unsigned short* As = Asm + sc * ASTG;
        const unsigned short* Bs = Bsm + sc * BSTG;
        sc = (sc == 2) ? 0 : sc + 1;
        short8 af[8], bf[4];
#pragma unroll
        for (int i = 0; i < 8; ++i) af[i] = *(const short8*)&As[ra[i]];
#pragma unroll
        for (int i = 0; i < 4; ++i) bf[i] = *(const short8*)&Bs[rc[i]];
#pragma unroll
        for (int rt = 0; rt < 8; ++rt)
#pragma unroll
            for (int ct = 0; ct < 4; ++ct)
                acc[rt][ct] = __builtin_amdgcn_mfma_f32_16x16x32_bf16(af[rt], bf[ct], acc[rt][ct], 0, 0, 0);
    }

    float ebv[4];
#pragma unroll
    for (int ct = 0; ct < 4; ++ct) {
        int vcol = colb + wcol + ct * 16 + fr;
        ebv[ct] = (vcol < V) ? ((bias != nullptr) ? __expf(bias[vcol]) : 1.0f) : 0.0f;
    }
#pragma unroll
    for (int rt = 0; rt < 8; ++rt) {
#pragma unroll
        for (int q = 0; q < 4; ++q) {
            float s = 0.f;
#pragma unroll
            for (int ct = 0; ct < 4; ++ct)
                s = fmaf(__expf(acc[rt][ct][q]), ebv[ct], s);
            s = row16_sum(s);
            if (fr == 0) cs[wrow + rt * 16 + fk * 4 + q][wave & 1] = s;
        }
    }
    __syncthreads();
    ps[(size_t)ch * NTOK + row_base + t] = cs[t][0] + cs[t][1];
}

// ---------------- prep: compact (blocks 0..15) + cvt of win/t0w1/t1w1/hw ----------------
__global__ __launch_bounds__(256)
void prep_k(const float* __restrict__ w_in, unsigned short* __restrict__ win_bf,
            const float* __restrict__ t0w1, unsigned short* __restrict__ t0w1_bf,
            const float* __restrict__ t1w1, unsigned short* __restrict__ t1w1_bf,
            const float* __restrict__ head_w, unsigned short* __restrict__ hw_bf,
            const int* __restrict__ target,
            int* __restrict__ idx0, int* __restrict__ lab0, int* __restrict__ n0,
            int* __restrict__ idx1, int* __restrict__ lab1, int* __restrict__ n1,
            int* __restrict__ labh) {
    int bid = blockIdx.x;
    if (bid < 16) {
        int i = bid * 256 + threadIdx.x;   // 4096 threads exactly, wave-uniform
        int t = target[i];
        int lane = threadIdx.x & 63;
        unsigned long long below = (1ull << lane) - 1ull;
        bool m0 = (t >= 2000) && (t < 10000);
        bool m1 = (t >= 10000);
        unsigned long long b0 = __ballot(m0);
        unsigned long long b1 = __ballot(m1);
        int ft = t;
        // wave-aggregated compaction: 1 atomic per wave per counter.
        if (m0) {
            int ldr = __ffsll((long long)b0) - 1;
            int base = 0;
            if (lane == ldr) base = atomicAdd(n0, __popcll(b0));
            base = __shfl(base, ldr, 64);
            int p = base + __popcll(b0 & below);
            idx0[p] = i; lab0[p] = t - 2000; ft = 2000;
        } else if (m1) {
            int ldr = __ffsll((long long)b1) - 1;
            int base = 0;
            if (lane == ldr) base = atomicAdd(n1, __popcll(b1));
            base = __shfl(base, ldr, 64);
            int p = base + __popcll(b1 & below);
            idx1[p] = i; lab1[p] = t - 10000; ft = 2001;
        }
        labh[i] = ft;
        return;
    }
    // cvt: flat float4 index over [w_in | t0w1 | t1w1 | head_w]
    const int E0 = 4194304, E1 = E0 + 1048576, E2 = E1 + 262144, TOT = E2 + 2050048;
    int gi = (bid - 16) * 256 + threadIdx.x;
    int stride = (gridDim.x - 16) * 256;
    for (int i4 = gi; i4 * 4 < TOT; i4 += stride) {
        int i = i4 * 4;
        const float* s; unsigned short* d; int off;
        if (i < E0)      { s = w_in;   d = win_bf;  off = i; }
        else if (i < E1) { s = t0w1;  d = t0w1_bf; off = i - E0; }
        else if (i < E2) { s = t1w1;  d = t1w1_bf; off = i - E1; }
        else             { s = head_w; d = hw_bf;   off = i - E2; }
        float4 v = *(const float4*)(s + off);
        ushort4 o;
        o.x = f2bf(v.x); o.y = f2bf(v.y); o.z = f2bf(v.z); o.w = f2bf(v.w);
        *(ushort4*)(d + off) = o;
    }
}

// ---------------- K2: hgemm (0..319) + cvt t0w2/t1w2 (320..1343) + head-ce (1344..1599) ----------------
// head-ce depends ONLY on K1 outputs (win_bf, hw_bf) -- moving it here overlaps
// its ~19us of MFMA work with the cvt's pure-BW work instead of serializing it
// into K3. LDS is a union: ce layout (75776B) is the superset.
__global__ __launch_bounds__(256, 2)
void hgemm_cvt_k(const unsigned short* __restrict__ win,
                 const unsigned short* __restrict__ t0w1, unsigned short* __restrict__ h0o,
                 const int* __restrict__ idx0, const int* __restrict__ n0p,
                 const unsigned short* __restrict__ t1w1, unsigned short* __restrict__ h1o,
                 const int* __restrict__ idx1, const int* __restrict__ n1p,
                 const float* __restrict__ t0w2, unsigned short* __restrict__ t0w2_bf,
                 const float* __restrict__ t1w2, unsigned short* __restrict__ t1w2_bf,
                 const unsigned short* __restrict__ hw, const float* __restrict__ head_b,
                 float* __restrict__ psh) {
    __shared__ __align__(16) char ldsraw[75776];
    int bid = blockIdx.x;
    if (bid >= 1344) {
        // head-ce: 256 blocks, rb-major (A-tile hot across consecutive bids)
        int b = bid - 1344;
        unsigned short* Asm = (unsigned short*)ldsraw;
        unsigned short* Bsm = (unsigned short*)(ldsraw + 49152);
        float (*cs)[2] = (float(*)[2])(ldsraw + 73728);
        ce_tile(win, hw, head_b, NTOK, 2002, 10, 32, b >> 4, b & 15, psh, Asm, Bsm, cs);
        return;
    }
    if (bid >= 320) {
        // cvt: flat float4 index over [t0w2 | t1w2]
        const int E0 = 8192000, TOT = 18432000;
        int gi = (bid - 320) * 256 + threadIdx.x;
        int stride = 1024 * 256;
        for (int i4 = gi; i4 * 4 < TOT; i4 += stride) {
            int i = i4 * 4;
            const float* s; unsigned short* d; int off;
            if (i < E0) { s = t0w2; d = t0w2_bf; off = i; }
            else        { s = t1w2; d = t1w2_bf; off = i - E0; }
            float4 v = *(const float4*)(s + off);
            ushort4 o;
            o.x = f2bf(v.x); o.y = f2bf(v.y); o.z = f2bf(v.z); o.w = f2bf(v.w);
            *(ushort4*)(d + off) = o;
        }
        return;
    }
    // hgemm: gathered-row GEMM into h0/h1
    unsigned short* Asm = (unsigned short*)ldsraw;            // 3*STG shorts
    unsigned short* Bsm = (unsigned short*)(ldsraw + 24576);  // 3*STG shorts
    int* sidx = (int*)(ldsraw + 49152);                       // 128 ints
    const unsigned short* B; unsigned short* H; const int* idx; int n, P, rb, cb;
    if (bid < 256) { rb = bid >> 3; cb = bid & 7; B = t0w1; H = h0o; idx = idx0; n = *n0p; P = 1024; }
    else { int b = bid - 256; rb = b >> 1; cb = b & 1; B = t1w1; H = h1o; idx = idx1; n = *n1p; P = 256; }
    const int K = 1024, T = 32;
    int row_base = rb * 128;
    if (row_base >= n) return;
    int col_base = cb * 128;
    int t = threadIdx.x;
    int wave = t >> 6, lane = t & 63;
    int wrow = (wave >> 1) * 64, wcol = (wave & 1) * 64;
    int fr = lane & 15, fk = lane >> 4;

    if (t < 128) { int r = row_base + t; sidx[t] = idx[r < n ? r : n - 1]; }
    __syncthreads();   // drains vmcnt: clean slate before manual pipeline (gather needs sidx)

    int sr0 = wave * 32 + (lane >> 2);
    int sr1 = sr0 + 16;
    int c0l = lane & 3;
    int gc0 = c0l ^ ((sr0 >> 1) & 3);
    int gc1 = c0l ^ ((sr1 >> 1) & 3);
    const unsigned short* Ab0 = win + (size_t)sidx[sr0] * K + gc0 * 8;
    const unsigned short* Ab1 = win + (size_t)sidx[sr1] * K + gc1 * 8;
    const unsigned short* Bb0 = B + (size_t)(col_base + sr0) * K + gc0 * 8;
    const unsigned short* Bb1 = B + (size_t)(col_base + sr1) * K + gc1 * 8;

    auto issue = [&](int s, int slot) {
        int koff = s << 5;
        unsigned short* as = Asm + slot * STG + wave * 1024;
        unsigned short* bs = Bsm + slot * STG + wave * 1024;
        gload16(Ab0 + koff, as); gload16(Ab1 + koff, as + 512);
        gload16(Bb0 + koff, bs); gload16(Bb1 + koff, bs + 512);
    };

    int sw = (fk ^ ((fr >> 1) & 3)) * 8;
    int ra[4], rc[4];
#pragma unroll
    for (int i = 0; i < 4; ++i) {
        ra[i] = (wrow + i * 16 + fr) * 32 + sw;
        rc[i] = (wcol + i * 16 + fr) * 32 + sw;
    }

    issue(0, 0); issue(1, 1);
    floatx4 acc[4][4] = {};
    int sc = 0, si = 2;
    for (int j = 0; j < T; ++j) {
        if (j + 2 < T) { issue(j + 2, si); si = (si == 2) ? 0 : si + 1; }
        int rem = T - 1 - j;
        if (rem >= 2) { WAIT_VM8(); }
        else if (rem == 1) { WAIT_VM4(); }
        else { WAIT_VM0(); }
        WAIT_LGKM();
        __builtin_amdgcn_s_barrier();
        const unsigned short* As = Asm + sc * STG;
        const unsigned short* Bs = Bsm + sc * STG;
        sc = (sc == 2) ? 0 : sc + 1;
        short8 af[4], bf[4];
#pragma unroll
        for (int i = 0; i < 4; ++i) af[i] = *(const short8*)&As[ra[i]];
#pragma unroll
        for (int i = 0; i < 4; ++i) bf[i] = *(const short8*)&Bs[rc[i]];
#pragma unroll
        for (int rt = 0; rt < 4; ++rt)
#pragma unroll
            for (int ct = 0; ct < 4; ++ct)
                acc[rt][ct] = __builtin_amdgcn_mfma_f32_16x16x32_bf16(af[rt], bf[ct], acc[rt][ct], 0, 0, 0);
    }
#pragma unroll
    for (int rt = 0; rt < 4; ++rt)
#pragma unroll
        for (int r = 0; r < 4; ++r) {
            int row = row_base + wrow + rt * 16 + fk * 4 + r;
#pragma unroll
            for (int ct = 0; ct < 4; ++ct) {
                int col = col_base + wcol + ct * 16 + fr;
                H[(size_t)row * P + col] = f2bf(acc[rt][ct][r]);
            }
        }
}

// ---------------- K3: ce tails, round-3 mapping (A-hot rb-major), heavy-first ----------------
// bid<1008:  tail0 V=8000  K=1024 T=32 {rb=bid/63, ch=bid%63}   (long blocks first)
// else:      tail1 V=40000 K=256  T=8  {rb=b/313, ch=b%313}     (short blocks fill tail)
__global__ __launch_bounds__(256, 2)
void ce_tails_k(const unsigned short* __restrict__ h1, const unsigned short* __restrict__ t1w2,
                const int* __restrict__ n1p, float* __restrict__ ps1,
                const unsigned short* __restrict__ h0, const unsigned short* __restrict__ t0w2,
                const int* __restrict__ n0p, float* __restrict__ ps0) {
    __shared__ unsigned short Asm[3 * ASTG];
    __shared__ unsigned short Bsm[3 * BSTG];
    __shared__ float cs[256][2];
    int bid = blockIdx.x;
    if (bid < 1008) {
        ce_tile(h0, t0w2, nullptr, *n0p, 8000, 10, 32, bid / 63, bid % 63, ps0, Asm, Bsm, cs);
    } else {
        int b = bid - 1008;
        ce_tile(h1, t1w2, nullptr, *n1p, 40000, 8, 8, b / 313, b % 313, ps1, Asm, Bsm, cs);
    }
}

// ---------------- reduce: wave-per-token LSE + label-logit dot + NLL ----------------
// One wave per token (12288 waves / 3072 blocks). 64-lane-parallel partial
// sums + bf16 K-dot for the label logit.
__global__ __launch_bounds__(256)
void reduce_all_k(const float* __restrict__ ps0, const unsigned short* __restrict__ h0,
                  const unsigned short* __restrict__ t0w2, const int* __restrict__ lab0,
                  const int* __restrict__ n0p,
                  const float* __restrict__ ps1, const unsigned short* __restrict__ h1,
                  const unsigned short* __restrict__ t1w2, const int* __restrict__ lab1,
                  const int* __restrict__ n1p,
                  const float* __restrict__ psh, const unsigned short* __restrict__ win,
                  const unsigned short* __restrict__ hw, const int* __restrict__ labh,
                  const float* __restrict__ head_b,
                  float* __restrict__ lossb) {
    __shared__ float part[4];
    int tid = threadIdx.x, lane = tid & 63, w = tid >> 6;
    int wid = blockIdx.x * 4 + w;
    int seg = wid >> 12, p = wid & 4095;
    const float* ps; const unsigned short* A; const unsigned short* B; const int* lab;
    int n, nc, kbits;
    if (seg == 0)      { ps = ps0; A = h0;  B = t0w2; lab = lab0; n = *n0p; nc = 63;  kbits = 10; }
    else if (seg == 1) { ps = ps1; A = h1;  B = t1w2; lab = lab1; n = *n1p; nc = 313; kbits = 8; }
    else               { ps = psh; A = win; B = hw;   lab = labh; n = NTOK; nc = 16;  kbits = 10; }
    float nll = 0.f;
    if (p < n) {                       // wave-uniform (p is per-wave)
        int L = lab[p];
        float S = 0.f;
        for (int c = lane; c < nc; c += 64) S += ps[(size_t)c * NTOK + p];
        int K = 1 << kbits;
        const unsigned short* ar = A + ((size_t)p << kbits);
        const unsigned short* br = B + ((size_t)L << kbits);
        float d = 0.f;
        for (int k = lane * 8; k < K; k += 512) {
            short8 av = *(const short8*)(ar + k);
            short8 bv = *(const short8*)(br + k);
#pragma unroll
            for (int e = 0; e < 8; ++e)
                d = fmaf(bf2f((unsigned short)av[e]), bf2f((unsigned short)bv[e]), d);
        }
#pragma unroll
        for (int off = 1; off < 64; off <<= 1) {
            S += __shfl_xor(S, off, 64);
            d += __shfl_xor(d, off, 64);
        }
        if (lane == 0) {
            float bias = (seg == 2) ? head_b[L] : 0.f;
            nll = logf(S) - d - bias;
        }
    }
    if (lane == 0) part[w] = nll;
    __syncthreads();
    if (tid == 0) atomicAdd(&lossb[blockIdx.x & 63], part[0] + part[1] + part[2] + part[3]);
}

__global__ void final_k(const float* __restrict__ lossb, float* __restrict__ out) {
    float v = lossb[threadIdx.x];
    for (int off = 32; off; off >>= 1) v += __shfl_down(v, off, 64);
    if (threadIdx.x == 0) out[0] = v * (1.0f / 4096.0f);
}

extern "C" void kernel_launch(void* const* d_in, const int* in_sizes, int n_in,
                              void* d_out, int out_size, void* d_ws, size_t ws_size,
                              hipStream_t stream) {
    const float* w_in   = (const float*)d_in[0];
    const int*   target = (const int*)d_in[1];
    const float* head_w = (const float*)d_in[2];
    const float* head_b = (const float*)d_in[3];
    const float* t0w1   = (const float*)d_in[4];
    const float* t0w2   = (const float*)d_in[5];
    const float* t1w1   = (const float*)d_in[6];
    const float* t1w2   = (const float*)d_in[7];
    float* out = (float*)d_out;

    char* wsb = (char*)d_ws;
    size_t o = 0;
    auto alloc = [&](size_t bytes) -> void* {
        void* p = wsb + o;
        o += (bytes + 255) & ~(size_t)255;
        return p;
    };
    float* lossb = (float*)alloc(64 * 4);   // 64 partial-loss buckets (offset 0)
    int* n0 = (int*)alloc(4);               // offset 256
    int* n1 = (int*)alloc(4);               // offset 512
    int* idx0 = (int*)alloc(NTOK * 4);
    int* lab0 = (int*)alloc(NTOK * 4);
    int* idx1 = (int*)alloc(NTOK * 4);
    int* lab1 = (int*)alloc(NTOK * 4);
    int* labh = (int*)alloc(NTOK * 4);

    const int SZ_WIN = NTOK * 1024, SZ_HW = 2002 * 1024, SZ_T0W1 = 1024 * 1024,
              SZ_T0W2 = 8000 * 1024, SZ_T1W1 = 256 * 1024, SZ_T1W2 = 40000 * 256;
    unsigned short* win_bf  = (unsigned short*)alloc((size_t)SZ_WIN * 2);
    unsigned short* hw_bf   = (unsigned short*)alloc((size_t)SZ_HW * 2);
    unsigned short* t0w1_bf = (unsigned short*)alloc((size_t)SZ_T0W1 * 2);
    unsigned short* t0w2_bf = (unsigned short*)alloc((size_t)SZ_T0W2 * 2);
    unsigned short* t1w1_bf = (unsigned short*)alloc((size_t)SZ_T1W1 * 2);
    unsigned short* t1w2_bf = (unsigned short*)alloc((size_t)SZ_T1W2 * 2);
    unsigned short* h0 = (unsigned short*)alloc((size_t)NTOK * 1024 * 2);
    unsigned short* h1 = (unsigned short*)alloc((size_t)NTOK * 256 * 2);

    const int NC0 = 63, NC1 = 313, NCH = 16;   // chunks per segment (per-chunk partials)
    float* ps0 = (float*)alloc((size_t)NC0 * NTOK * 4);
    float* ps1 = (float*)alloc((size_t)NC1 * NTOK * 4);
    float* psh = (float*)alloc((size_t)NCH * NTOK * 4);

    dim3 blk(256);
    hipMemsetAsync(d_ws, 0, 768, stream);   // zero lossb, n0, n1

    // K1: compact (16) + cvt of win/t0w1/t1w1/hw (1376 blocks)
    prep_k<<<16 + 1376, blk, 0, stream>>>(
        w_in, win_bf, t0w1, t0w1_bf, t1w1, t1w1_bf, head_w, hw_bf,
        target, idx0, lab0, n0, idx1, lab1, n1, labh);

    // K2: hgemm (320) + cvt of t0w2/t1w2 (1024) + head-ce (256)
    hgemm_cvt_k<<<1600, blk, 0, stream>>>(
        win_bf, t0w1_bf, h0, idx0, n0, t1w1_bf, h1, idx1, n1,
        t0w2, t0w2_bf, t1w2, t1w2_bf, hw_bf, head_b, psh);

    // K3: tail ce only, heavy-first: tail0 (1008) then tail1 (5008)
    ce_tails_k<<<1008 + 5008, blk, 0, stream>>>(
        h1, t1w2_bf, n1, ps1,
        h0, t0w2_bf, n0, ps0);

    // K4: one wave per token: 3*4096 waves, 4 waves/block -> 3072 blocks
    reduce_all_k<<<3 * NTOK / 4, blk, 0, stream>>>(
        ps0, h0, t0w2_bf, lab0, n0,
        ps1, h1, t1w2_bf, lab1, n1,
        psh, win_bf, hw_bf, labh, head_b, lossb);

    final_k<<<1, 64, 0, stream>>>(lossb, out);
}